// Round 13
// baseline (197.202 us; speedup 1.0000x reference)
//
#include <hip/hip_runtime.h>
#include <hip/hip_bf16.h>
#include <math.h>

// Problem constants (from reference)
#define B_ROWS 4096
#define C_ROWS 2048
#define D_DIM  2048
#define NUM 2
#define MAX_ITER 15
#define NEAREST 3
#define MARGIN 1.0f

typedef __bf16 bf16_t;
typedef bf16_t bf16x8 __attribute__((ext_vector_type(8)));
typedef float f32x4 __attribute__((ext_vector_type(4)));
typedef long fp8x8;                 // 8 fp8 bytes = one MFMA fragment (2 VGPRs)
typedef unsigned char u8;

// ---------------------------------------------------------------------------
// conv: one wave per row, f32 -> fp8 e4m3 (HW cvt_pk, OCP-native on gfx950)
// + row sumsq (exact, from f32) via shuffle.
// Rows [0,4096) = feature, [4096,6144) = centers. 4 waves/block.
// Block 0 zero-inits out (select accumulates onto it; stream order).
// ---------------------------------------------------------------------------
__global__ __launch_bounds__(256) void conv_rows(const float* __restrict__ F,
                                                 const float* __restrict__ Cn,
                                                 u8* __restrict__ Fq,
                                                 u8* __restrict__ Cq,
                                                 float* __restrict__ f2,
                                                 float* __restrict__ c2,
                                                 float* __restrict__ out) {
    if (blockIdx.x == 0 && threadIdx.x == 0) out[0] = 0.0f;
    int wave = threadIdx.x >> 6;
    int lane = threadIdx.x & 63;
    int row = blockIdx.x * 4 + wave;          // 0..6143
    const float* p; u8* q; float* sq; int r;
    if (row < B_ROWS) {
        r = row; p = F + (size_t)r * D_DIM; q = Fq + (size_t)r * D_DIM; sq = f2;
    } else {
        r = row - B_ROWS; p = Cn + (size_t)r * D_DIM; q = Cq + (size_t)r * D_DIM; sq = c2;
    }
    float s = 0.0f;
    #pragma unroll
    for (int it = 0; it < 4; ++it) {
        int k = (it * 64 + lane) * 8;         // 8 consecutive floats per lane
        float4 v0 = *(const float4*)(p + k);
        float4 v1 = *(const float4*)(p + k + 4);
        s += v0.x * v0.x + v0.y * v0.y + v0.z * v0.z + v0.w * v0.w;
        s += v1.x * v1.x + v1.y * v1.y + v1.z * v1.z + v1.w * v1.w;
        int lo = __builtin_amdgcn_cvt_pk_fp8_f32(v0.x, v0.y, 0, 0);
        lo     = __builtin_amdgcn_cvt_pk_fp8_f32(v0.z, v0.w, lo, 1);
        int hi = __builtin_amdgcn_cvt_pk_fp8_f32(v1.x, v1.y, 0, 0);
        hi     = __builtin_amdgcn_cvt_pk_fp8_f32(v1.z, v1.w, hi, 1);
        int2 st; st.x = lo; st.y = hi;
        *(int2*)(q + k) = st;                 // 8 bytes, coalesced
    }
    #pragma unroll
    for (int off = 32; off >= 1; off >>= 1) s += __shfl_down(s, off);
    if (lane == 0) sq[r] = s;
}

// ---------------------------------------------------------------------------
// Fused fp8 MFMA distance GEMM (Dfc and Dcc in one dispatch).
// fp8 e4m3 inputs (same MFMA rate as bf16 but half the bytes everywhere):
//  - BK=128 as two [128 rows][64 B] K-panels at unchanged 32 KB LDS ->
//    one barrier drain per 128 K-elements (quarter of the R10 bf16 config).
//  - staging: 16-row x 64 B segments, consecutive-4-lane coalescing (the
//    measured-good pattern); 8 instrs/wave per K-iter (halved).
//  - fragment reads: ds_read_b64, same 8-way aliasing, half the cycles.
// MEASURED PITFALLS (do not revisit): R5 128B-row banking; R7 nonzero imm
// offset on global_load_lds; R11 fragment-ordered staging breaks coalescing.
// 128x128 tile, 4 waves (2x2 of 64x64), 16x16x32 fp8 MFMA.
//   Out[m][n] = bf16( a2[m] + c2[n] - 2 * sum_k A[m][k]*Cb[n][k] )
// ---------------------------------------------------------------------------
__global__ __launch_bounds__(256, 3) void gemm_d2_fused(const u8* __restrict__ Fq,
                                                        const u8* __restrict__ Cq,
                                                        const float* __restrict__ f2,
                                                        const float* __restrict__ c2,
                                                        bf16_t* __restrict__ Dfc,
                                                        bf16_t* __restrict__ Dcc) {
    __shared__ __align__(16) u8 As[2][128 * 64];   // [panel][row*64 + kbyte]
    __shared__ __align__(16) u8 Bs[2][128 * 64];

    const int tid  = threadIdx.x;
    const int wave = tid >> 6;
    const int lane = tid & 63;

    const int by = blockIdx.y;
    const u8* A; const float* a2v; bf16_t* Out; int bm;
    if (by < B_ROWS / 128) { A = Fq; a2v = f2; Out = Dfc; bm = by * 128; }
    else { A = Cq; a2v = c2; Out = Dcc; bm = (by - B_ROWS / 128) * 128; }
    const int bn = blockIdx.x * 128;
    const int N = C_ROWS, K = D_DIM;

    const int wm = (wave >> 1) * 64;
    const int wn = (wave & 1) * 64;

    f32x4 acc[4][4] = {};

    const int c0   = wave * 2;            // chunks 2w, 2w+1 (16 rows each)
    const int rsub = lane >> 2;           // 0..15 row within chunk
    const int kbyt = (lane & 3) * 16;     // byte offset within 64B row
    const int mrow = lane & 15;
    const int kq8  = (lane >> 4) * 8;     // fragment k-byte offset 0,8,16,24

    for (int k0 = 0; k0 < K; k0 += 128) {
        #pragma unroll
        for (int pn = 0; pn < 2; ++pn) {       // K-panel: k0 + pn*64 + [0,64)
            #pragma unroll
            for (int t = 0; t < 2; ++t) {
                int chunk = c0 + t;
                int row = chunk * 16 + rsub;
                const u8* gA = A  + (size_t)(bm + row) * K + (k0 + pn * 64 + kbyt);
                const u8* gB = Cq + (size_t)(bn + row) * K + (k0 + pn * 64 + kbyt);
                __builtin_amdgcn_global_load_lds(
                    (const __attribute__((address_space(1))) void*)gA,
                    (__attribute__((address_space(3))) void*)&As[pn][chunk * 1024], 16, 0, 0);
                __builtin_amdgcn_global_load_lds(
                    (const __attribute__((address_space(1))) void*)gB,
                    (__attribute__((address_space(3))) void*)&Bs[pn][chunk * 1024], 16, 0, 0);
            }
        }
        __syncthreads();

        #pragma unroll
        for (int s = 0; s < 4; ++s) {          // 4 k-steps of 32 within BK=128
            const int pn   = s >> 1;
            const int koff = (s & 1) * 32;
            fp8x8 af[4], bf_[4];
            #pragma unroll
            for (int i = 0; i < 4; ++i) {
                af[i]  = *(const fp8x8*)&As[pn][(wm + i * 16 + mrow) * 64 + koff + kq8];
                bf_[i] = *(const fp8x8*)&Bs[pn][(wn + i * 16 + mrow) * 64 + koff + kq8];
            }
            #pragma unroll
            for (int i = 0; i < 4; ++i)
                #pragma unroll
                for (int j = 0; j < 4; ++j)
                    acc[i][j] = __builtin_amdgcn_mfma_f32_16x16x32_fp8_fp8(af[i], bf_[j], acc[i][j], 0, 0, 0);
        }
        __syncthreads();
    }

    // Epilogue: d2 = a2[m] + c2[n] - 2*dot, stored bf16.
    // C/D layout is shape-determined, dtype-independent: col=lane&15,
    // row=(lane>>4)*4+reg
    const int ncol = lane & 15;
    const int r4   = (lane >> 4) * 4;
    #pragma unroll
    for (int i = 0; i < 4; ++i) {
        #pragma unroll
        for (int r = 0; r < 4; ++r) {
            int m = bm + wm + i * 16 + r4 + r;
            float am = a2v[m];
            #pragma unroll
            for (int j = 0; j < 4; ++j) {
                int n = bn + wn + j * 16 + ncol;
                Out[(size_t)m * N + n] = (bf16_t)(am + c2[n] - 2.0f * acc[i][j][r]);
            }
        }
    }
}

// ---------------------------------------------------------------------------
// select v3: bf16 distance rows, vectorized 16B loads.
// Iterative argmin w/ exclusion over Dfc row; on-demand trust from Dcc:
//   label in near3[sel]  <=>  #{ j : (Dcc[sel][j], j) <lex (Dcc[sel][label],
//   label) } < NEAREST   (stable argsort -> lexicographic order)
// Ownership: lane l, group g, sub e: n = g*512 + l*8 + e; excl bit g*8+e.
// 4 waves/block, one row per wave; one atomicAdd per block onto out.
// ---------------------------------------------------------------------------
__global__ __launch_bounds__(256) void select_kernel(const bf16_t* __restrict__ Dfc,
                                                     const bf16_t* __restrict__ Dcc,
                                                     float* __restrict__ out, int C) {
    int wave = threadIdx.x >> 6, lane = threadIdx.x & 63;
    int b = blockIdx.x * 4 + wave;
    int label = b / NUM;
    const bf16_t* row = Dfc + (size_t)b * C;

    float vals[32];
    #pragma unroll
    for (int g = 0; g < 4; ++g) {
        bf16x8 v = *(const bf16x8*)(row + g * 512 + lane * 8);
        #pragma unroll
        for (int e = 0; e < 8; ++e) {
            int n = g * 512 + lane * 8 + e;
            float f = (float)v[e];
            vals[g * 8 + e] = (n == label) ? INFINITY : f;
        }
    }

    unsigned int excl = 0;
    float min_diff = 0.0f;
    int found = 0;
    for (int it = 0; it < MAX_ITER; ++it) {
        float bestv = INFINITY; int bestidx = 0x7fffffff;
        #pragma unroll
        for (int g = 0; g < 4; ++g)
            #pragma unroll
            for (int e = 0; e < 8; ++e) {
                int bit = g * 8 + e;
                if (excl & (1u << bit)) continue;
                float v = vals[bit];
                int idx = g * 512 + lane * 8 + e;
                if (v < bestv || (v == bestv && idx < bestidx)) { bestv = v; bestidx = idx; }
            }
        for (int off = 32; off >= 1; off >>= 1) {
            float ov = __shfl_down(bestv, off); int oi = __shfl_down(bestidx, off);
            if (ov < bestv || (ov == bestv && oi < bestidx)) { bestv = ov; bestidx = oi; }
        }
        int sel = __shfl(bestidx, 0);
        float selv = __shfl(bestv, 0);

        // --- on-demand trust: count lex-smaller entries of Dcc row sel ---
        const bf16_t* crow = Dcc + (size_t)sel * C;
        float dl = (float)crow[label];          // uniform address: broadcast
        int cnt = 0;
        #pragma unroll
        for (int g = 0; g < 4; ++g) {
            bf16x8 v = *(const bf16x8*)(crow + g * 512 + lane * 8);
            #pragma unroll
            for (int e = 0; e < 8; ++e) {
                int idx = g * 512 + lane * 8 + e;
                float f = (float)v[e];
                cnt += (f < dl || (f == dl && idx < label)) ? 1 : 0;
            }
        }
        #pragma unroll
        for (int off = 32; off >= 1; off >>= 1) cnt += __shfl_down(cnt, off);
        cnt = __shfl(cnt, 0);
        bool trusted = (cnt >= NEAREST);

        if (trusted) { min_diff = sqrtf(fmaxf(selv, 0.0f)); found = 1; break; }
        if (((sel >> 3) & 63) == lane) excl |= 1u << (((sel >> 9) << 3) | (sel & 7));
    }
    __shared__ float hs[4];
    if (lane == 0) {
        float same = sqrtf(fmaxf((float)row[label], 0.0f));
        float md = found ? min_diff : 0.0f;
        hs[wave] = fmaxf(MARGIN + same - md, 0.0f);
    }
    __syncthreads();
    if (threadIdx.x == 0)
        atomicAdd(out, (hs[0] + hs[1] + hs[2] + hs[3]) * (1.0f / (float)B_ROWS));
}

// ---------------------------------------------------------------------------
extern "C" void kernel_launch(void* const* d_in, const int* in_sizes, int n_in,
                              void* d_out, int out_size, void* d_ws, size_t ws_size,
                              hipStream_t stream) {
    const float* feature = (const float*)d_in[0];  // 4096 x 2048
    const float* centers = (const float*)d_in[1];  // 2048 x 2048
    float* out = (float*)d_out;                    // scalar

    // Workspace layout (distances bf16, quantized inputs fp8)
    bf16_t* Dfc  = (bf16_t*)d_ws;                            // 4096*2048 bf16
    bf16_t* Dcc  = Dfc + (size_t)B_ROWS * C_ROWS;            // 2048*2048 bf16
    u8*     Fq   = (u8*)(Dcc + (size_t)C_ROWS * C_ROWS);     // 4096*2048 fp8
    u8*     Cq   = Fq + (size_t)B_ROWS * D_DIM;              // 2048*2048 fp8
    float*  f2   = (float*)(Cq + (size_t)C_ROWS * D_DIM);    // 4096
    float*  c2   = f2 + B_ROWS;                              // 2048

    conv_rows<<<(B_ROWS + C_ROWS) / 4, 256, 0, stream>>>(feature, centers, Fq, Cq,
                                                         f2, c2, out);

    // Both distance matrices in one dispatch: grid (16, 32+16) = 768 blocks.
    gemm_d2_fused<<<dim3(C_ROWS / 128, B_ROWS / 128 + C_ROWS / 128), 256, 0, stream>>>(
        Fq, Cq, f2, c2, Dfc, Dcc);

    // select with on-demand trust (reads Dcc directly; no near3 dispatch).
    select_kernel<<<B_ROWS / 4, 256, 0, stream>>>(Dfc, Dcc, out, C_ROWS);
}

// Round 14
// 142.201 us; speedup vs baseline: 1.3868x; 1.3868x over previous
//
#include <hip/hip_runtime.h>
#include <hip/hip_bf16.h>
#include <math.h>

// Problem constants (from reference)
#define B_ROWS 4096
#define C_ROWS 2048
#define D_DIM  2048
#define NUM 2
#define MAX_ITER 15
#define NEAREST 3
#define MARGIN 1.0f

typedef __bf16 bf16_t;
typedef bf16_t bf16x8 __attribute__((ext_vector_type(8)));
typedef float f32x4 __attribute__((ext_vector_type(4)));
typedef long fp8x8;                 // 8 fp8 bytes = one MFMA fragment (2 VGPRs)
typedef unsigned char u8;

// ---------------------------------------------------------------------------
// conv: one wave per row, f32 -> fp8 e4m3 (HW cvt_pk, OCP-native on gfx950)
// + row sumsq (exact, from f32) via shuffle. Verified R13: absmax 0.0.
// Rows [0,4096) = feature, [4096,6144) = centers. 4 waves/block.
// Block 0 zero-inits out (select accumulates onto it; stream order).
// ---------------------------------------------------------------------------
__global__ __launch_bounds__(256) void conv_rows(const float* __restrict__ F,
                                                 const float* __restrict__ Cn,
                                                 u8* __restrict__ Fq,
                                                 u8* __restrict__ Cq,
                                                 float* __restrict__ f2,
                                                 float* __restrict__ c2,
                                                 float* __restrict__ out) {
    if (blockIdx.x == 0 && threadIdx.x == 0) out[0] = 0.0f;
    int wave = threadIdx.x >> 6;
    int lane = threadIdx.x & 63;
    int row = blockIdx.x * 4 + wave;          // 0..6143
    const float* p; u8* q; float* sq; int r;
    if (row < B_ROWS) {
        r = row; p = F + (size_t)r * D_DIM; q = Fq + (size_t)r * D_DIM; sq = f2;
    } else {
        r = row - B_ROWS; p = Cn + (size_t)r * D_DIM; q = Cq + (size_t)r * D_DIM; sq = c2;
    }
    float s = 0.0f;
    #pragma unroll
    for (int it = 0; it < 4; ++it) {
        int k = (it * 64 + lane) * 8;         // 8 consecutive floats per lane
        float4 v0 = *(const float4*)(p + k);
        float4 v1 = *(const float4*)(p + k + 4);
        s += v0.x * v0.x + v0.y * v0.y + v0.z * v0.z + v0.w * v0.w;
        s += v1.x * v1.x + v1.y * v1.y + v1.z * v1.z + v1.w * v1.w;
        int lo = __builtin_amdgcn_cvt_pk_fp8_f32(v0.x, v0.y, 0, 0);
        lo     = __builtin_amdgcn_cvt_pk_fp8_f32(v0.z, v0.w, lo, 1);
        int hi = __builtin_amdgcn_cvt_pk_fp8_f32(v1.x, v1.y, 0, 0);
        hi     = __builtin_amdgcn_cvt_pk_fp8_f32(v1.z, v1.w, hi, 1);
        int2 st; st.x = lo; st.y = hi;
        *(int2*)(q + k) = st;                 // 8 bytes, coalesced
    }
    #pragma unroll
    for (int off = 32; off >= 1; off >>= 1) s += __shfl_down(s, off);
    if (lane == 0) sq[r] = s;
}

// ---------------------------------------------------------------------------
// Fused fp8 MFMA distance GEMM with XOR BANK SWIZZLE.
// R13 post-mortem: fp8 BK=128 halved FETCH (99->50MB) but b64 fragment reads
// at 64B row stride hit 4.4e7 bank-conflict cycles (8-way). Fix: store 16B
// chunk c of row r at LDS slot (c ^ ((r>>1)&3)). This is a WITHIN-ROW lane
// permutation: each 4-lane staging group still covers the same 64B global
// segment (coalescing identical — R11's row-scatter failure does not apply),
// while fragment reads now spread 16 rows over 8 bank positions -> 2-way
// aliasing, which is free (m136).
// MEASURED PITFALLS (do not revisit): R5 128B-row banking; R7 nonzero imm
// offset on global_load_lds; R11 per-lane ROW scatter breaks coalescing.
// 128x128 tile, 4 waves (2x2 of 64x64), 16x16x32 fp8 MFMA, BK=128 as two
// [128 rows][64 B] K-panels (one barrier drain per 128 K-elements).
//   Out[m][n] = bf16( a2[m] + c2[n] - 2 * sum_k A[m][k]*Cb[n][k] )
// ---------------------------------------------------------------------------
__global__ __launch_bounds__(256, 3) void gemm_d2_fused(const u8* __restrict__ Fq,
                                                        const u8* __restrict__ Cq,
                                                        const float* __restrict__ f2,
                                                        const float* __restrict__ c2,
                                                        bf16_t* __restrict__ Dfc,
                                                        bf16_t* __restrict__ Dcc) {
    __shared__ __align__(16) u8 As[2][128 * 64];   // [panel][row*64 + swizzled]
    __shared__ __align__(16) u8 Bs[2][128 * 64];

    const int tid  = threadIdx.x;
    const int wave = tid >> 6;
    const int lane = tid & 63;

    const int by = blockIdx.y;
    const u8* A; const float* a2v; bf16_t* Out; int bm;
    if (by < B_ROWS / 128) { A = Fq; a2v = f2; Out = Dfc; bm = by * 128; }
    else { A = Cq; a2v = c2; Out = Dcc; bm = (by - B_ROWS / 128) * 128; }
    const int bn = blockIdx.x * 128;
    const int N = C_ROWS, K = D_DIM;

    const int wm = (wave >> 1) * 64;
    const int wn = (wave & 1) * 64;

    f32x4 acc[4][4] = {};

    const int c0   = wave * 2;            // chunks 2w, 2w+1 (16 rows each)
    const int rsub = lane >> 2;           // 0..15 row within chunk
    // swizzled global source chunk: slot (lane&3) holds chunk (lane&3)^sw,
    // sw = (row>>1)&3 = (rsub>>1)&3 = (lane>>3)&3   (chunk*16 contributes 0)
    const int kbyt = ((lane & 3) ^ ((lane >> 3) & 3)) * 16;
    const int mrow = lane & 15;
    const int swr  = (mrow >> 1) & 3;     // read-side swizzle for this lane's rows
    const int kq8  = (lane >> 4) * 8;     // fragment k-byte offset 0,8,16,24

    for (int k0 = 0; k0 < K; k0 += 128) {
        #pragma unroll
        for (int pn = 0; pn < 2; ++pn) {       // K-panel: k0 + pn*64 + [0,64)
            #pragma unroll
            for (int t = 0; t < 2; ++t) {
                int chunk = c0 + t;
                int row = chunk * 16 + rsub;
                const u8* gA = A  + (size_t)(bm + row) * K + (k0 + pn * 64 + kbyt);
                const u8* gB = Cq + (size_t)(bn + row) * K + (k0 + pn * 64 + kbyt);
                __builtin_amdgcn_global_load_lds(
                    (const __attribute__((address_space(1))) void*)gA,
                    (__attribute__((address_space(3))) void*)&As[pn][chunk * 1024], 16, 0, 0);
                __builtin_amdgcn_global_load_lds(
                    (const __attribute__((address_space(1))) void*)gB,
                    (__attribute__((address_space(3))) void*)&Bs[pn][chunk * 1024], 16, 0, 0);
            }
        }
        __syncthreads();

        #pragma unroll
        for (int s = 0; s < 4; ++s) {          // 4 k-steps of 32 within BK=128
            const int pn = s >> 1;
            const int kb = (s & 1) * 32 + kq8; // byte pos 0..56 within 64B row
            const int sl = ((kb >> 4) ^ swr) << 4;  // swizzled 16B slot
            const int wi = kb & 15;                 // 0 or 8 within slot
            fp8x8 af[4], bf_[4];
            #pragma unroll
            for (int i = 0; i < 4; ++i) {
                af[i]  = *(const fp8x8*)&As[pn][(wm + i * 16 + mrow) * 64 + sl + wi];
                bf_[i] = *(const fp8x8*)&Bs[pn][(wn + i * 16 + mrow) * 64 + sl + wi];
            }
            #pragma unroll
            for (int i = 0; i < 4; ++i)
                #pragma unroll
                for (int j = 0; j < 4; ++j)
                    acc[i][j] = __builtin_amdgcn_mfma_f32_16x16x32_fp8_fp8(af[i], bf_[j], acc[i][j], 0, 0, 0);
        }
        __syncthreads();
    }

    // Epilogue: d2 = a2[m] + c2[n] - 2*dot, stored bf16.
    // C/D layout shape-determined, dtype-independent: col=lane&15,
    // row=(lane>>4)*4+reg
    const int ncol = lane & 15;
    const int r4   = (lane >> 4) * 4;
    #pragma unroll
    for (int i = 0; i < 4; ++i) {
        #pragma unroll
        for (int r = 0; r < 4; ++r) {
            int m = bm + wm + i * 16 + r4 + r;
            float am = a2v[m];
            #pragma unroll
            for (int j = 0; j < 4; ++j) {
                int n = bn + wn + j * 16 + ncol;
                Out[(size_t)m * N + n] = (bf16_t)(am + c2[n] - 2.0f * acc[i][j][r]);
            }
        }
    }
}

// ---------------------------------------------------------------------------
// select v3: bf16 distance rows, vectorized 16B loads.
// Iterative argmin w/ exclusion over Dfc row; on-demand trust from Dcc:
//   label in near3[sel]  <=>  #{ j : (Dcc[sel][j], j) <lex (Dcc[sel][label],
//   label) } < NEAREST   (stable argsort -> lexicographic order)
// Ownership: lane l, group g, sub e: n = g*512 + l*8 + e; excl bit g*8+e.
// 4 waves/block, one row per wave; one atomicAdd per block onto out.
// ---------------------------------------------------------------------------
__global__ __launch_bounds__(256) void select_kernel(const bf16_t* __restrict__ Dfc,
                                                     const bf16_t* __restrict__ Dcc,
                                                     float* __restrict__ out, int C) {
    int wave = threadIdx.x >> 6, lane = threadIdx.x & 63;
    int b = blockIdx.x * 4 + wave;
    int label = b / NUM;
    const bf16_t* row = Dfc + (size_t)b * C;

    float vals[32];
    #pragma unroll
    for (int g = 0; g < 4; ++g) {
        bf16x8 v = *(const bf16x8*)(row + g * 512 + lane * 8);
        #pragma unroll
        for (int e = 0; e < 8; ++e) {
            int n = g * 512 + lane * 8 + e;
            float f = (float)v[e];
            vals[g * 8 + e] = (n == label) ? INFINITY : f;
        }
    }

    unsigned int excl = 0;
    float min_diff = 0.0f;
    int found = 0;
    for (int it = 0; it < MAX_ITER; ++it) {
        float bestv = INFINITY; int bestidx = 0x7fffffff;
        #pragma unroll
        for (int g = 0; g < 4; ++g)
            #pragma unroll
            for (int e = 0; e < 8; ++e) {
                int bit = g * 8 + e;
                if (excl & (1u << bit)) continue;
                float v = vals[bit];
                int idx = g * 512 + lane * 8 + e;
                if (v < bestv || (v == bestv && idx < bestidx)) { bestv = v; bestidx = idx; }
            }
        for (int off = 32; off >= 1; off >>= 1) {
            float ov = __shfl_down(bestv, off); int oi = __shfl_down(bestidx, off);
            if (ov < bestv || (ov == bestv && oi < bestidx)) { bestv = ov; bestidx = oi; }
        }
        int sel = __shfl(bestidx, 0);
        float selv = __shfl(bestv, 0);

        // --- on-demand trust: count lex-smaller entries of Dcc row sel ---
        const bf16_t* crow = Dcc + (size_t)sel * C;
        float dl = (float)crow[label];          // uniform address: broadcast
        int cnt = 0;
        #pragma unroll
        for (int g = 0; g < 4; ++g) {
            bf16x8 v = *(const bf16x8*)(crow + g * 512 + lane * 8);
            #pragma unroll
            for (int e = 0; e < 8; ++e) {
                int idx = g * 512 + lane * 8 + e;
                float f = (float)v[e];
                cnt += (f < dl || (f == dl && idx < label)) ? 1 : 0;
            }
        }
        #pragma unroll
        for (int off = 32; off >= 1; off >>= 1) cnt += __shfl_down(cnt, off);
        cnt = __shfl(cnt, 0);
        bool trusted = (cnt >= NEAREST);

        if (trusted) { min_diff = sqrtf(fmaxf(selv, 0.0f)); found = 1; break; }
        if (((sel >> 3) & 63) == lane) excl |= 1u << (((sel >> 9) << 3) | (sel & 7));
    }
    __shared__ float hs[4];
    if (lane == 0) {
        float same = sqrtf(fmaxf((float)row[label], 0.0f));
        float md = found ? min_diff : 0.0f;
        hs[wave] = fmaxf(MARGIN + same - md, 0.0f);
    }
    __syncthreads();
    if (threadIdx.x == 0)
        atomicAdd(out, (hs[0] + hs[1] + hs[2] + hs[3]) * (1.0f / (float)B_ROWS));
}

// ---------------------------------------------------------------------------
extern "C" void kernel_launch(void* const* d_in, const int* in_sizes, int n_in,
                              void* d_out, int out_size, void* d_ws, size_t ws_size,
                              hipStream_t stream) {
    const float* feature = (const float*)d_in[0];  // 4096 x 2048
    const float* centers = (const float*)d_in[1];  // 2048 x 2048
    float* out = (float*)d_out;                    // scalar

    // Workspace layout (distances bf16, quantized inputs fp8)
    bf16_t* Dfc  = (bf16_t*)d_ws;                            // 4096*2048 bf16
    bf16_t* Dcc  = Dfc + (size_t)B_ROWS * C_ROWS;            // 2048*2048 bf16
    u8*     Fq   = (u8*)(Dcc + (size_t)C_ROWS * C_ROWS);     // 4096*2048 fp8
    u8*     Cq   = Fq + (size_t)B_ROWS * D_DIM;              // 2048*2048 fp8
    float*  f2   = (float*)(Cq + (size_t)C_ROWS * D_DIM);    // 4096
    float*  c2   = f2 + B_ROWS;                              // 2048

    conv_rows<<<(B_ROWS + C_ROWS) / 4, 256, 0, stream>>>(feature, centers, Fq, Cq,
                                                         f2, c2, out);

    // Both distance matrices in one dispatch: grid (16, 32+16) = 768 blocks.
    gemm_d2_fused<<<dim3(C_ROWS / 128, B_ROWS / 128 + C_ROWS / 128), 256, 0, stream>>>(
        Fq, Cq, f2, c2, Dfc, Dcc);

    // select with on-demand trust (reads Dcc directly; no near3 dispatch).
    select_kernel<<<B_ROWS / 4, 256, 0, stream>>>(Dfc, Dcc, out, C_ROWS);
}

// Round 15
// 135.111 us; speedup vs baseline: 1.4596x; 1.0525x over previous
//
#include <hip/hip_runtime.h>
#include <hip/hip_bf16.h>
#include <math.h>

// Problem constants (from reference)
#define B_ROWS 4096
#define C_ROWS 2048
#define D_DIM  2048
#define NUM 2
#define MAX_ITER 15
#define NEAREST 3
#define MARGIN 1.0f

typedef __bf16 bf16_t;
typedef bf16_t bf16x8 __attribute__((ext_vector_type(8)));
typedef float f32x4 __attribute__((ext_vector_type(4)));
typedef int i32x4 __attribute__((ext_vector_type(4)));
typedef int i32x8 __attribute__((ext_vector_type(8)));   // 32 fp8 bytes = scaled-MFMA fragment
typedef unsigned char u8;

// ---------------------------------------------------------------------------
// conv: one wave per row, f32 -> fp8 e4m3 (HW cvt_pk, OCP-native on gfx950)
// + row sumsq (exact, from f32) via shuffle. Verified R13/R14: absmax 0.0.
// Rows [0,4096) = feature, [4096,6144) = centers. 4 waves/block.
// Block 0 zero-inits out (select accumulates onto it; stream order).
// ---------------------------------------------------------------------------
__global__ __launch_bounds__(256) void conv_rows(const float* __restrict__ F,
                                                 const float* __restrict__ Cn,
                                                 u8* __restrict__ Fq,
                                                 u8* __restrict__ Cq,
                                                 float* __restrict__ f2,
                                                 float* __restrict__ c2,
                                                 float* __restrict__ out) {
    if (blockIdx.x == 0 && threadIdx.x == 0) out[0] = 0.0f;
    int wave = threadIdx.x >> 6;
    int lane = threadIdx.x & 63;
    int row = blockIdx.x * 4 + wave;          // 0..6143
    const float* p; u8* q; float* sq; int r;
    if (row < B_ROWS) {
        r = row; p = F + (size_t)r * D_DIM; q = Fq + (size_t)r * D_DIM; sq = f2;
    } else {
        r = row - B_ROWS; p = Cn + (size_t)r * D_DIM; q = Cq + (size_t)r * D_DIM; sq = c2;
    }
    float s = 0.0f;
    #pragma unroll
    for (int it = 0; it < 4; ++it) {
        int k = (it * 64 + lane) * 8;         // 8 consecutive floats per lane
        float4 v0 = *(const float4*)(p + k);
        float4 v1 = *(const float4*)(p + k + 4);
        s += v0.x * v0.x + v0.y * v0.y + v0.z * v0.z + v0.w * v0.w;
        s += v1.x * v1.x + v1.y * v1.y + v1.z * v1.z + v1.w * v1.w;
        int lo = __builtin_amdgcn_cvt_pk_fp8_f32(v0.x, v0.y, 0, 0);
        lo     = __builtin_amdgcn_cvt_pk_fp8_f32(v0.z, v0.w, lo, 1);
        int hi = __builtin_amdgcn_cvt_pk_fp8_f32(v1.x, v1.y, 0, 0);
        hi     = __builtin_amdgcn_cvt_pk_fp8_f32(v1.z, v1.w, hi, 1);
        int2 st; st.x = lo; st.y = hi;
        *(int2*)(q + k) = st;                 // 8 bytes, coalesced
    }
    #pragma unroll
    for (int off = 32; off >= 1; off >>= 1) s += __shfl_down(s, off);
    if (lane == 0) sq[r] = s;
}

// ---------------------------------------------------------------------------
// Fused fp8 distance GEMM, MX-SCALED K=128 MFMA (scale = 1.0 -> arithmetic
// identical to plain fp8; just 2x the per-instruction K depth at the
// f8f6f4 rate — m148: 1628 vs 995 TF on this structure).
// Layout (R14, measured 47.3us): BK=128 as two [128 rows][64 B] K-panels;
// XOR bank swizzle — 16B chunk c of row r lives at slot c ^ ((r>>1)&3);
// staging via global_load_lds keeps 4-lane/64B coalescing (the swizzle is a
// within-row lane permutation, NOT the R11 row-scatter).
// Fragment for mfma_scale_f32_16x16x128_f8f6f4: lane l holds 32 k-bytes,
// row = l&15, k-group kg = l>>4 -> panel kg>>1, 32B-half kg&1 -> two fixed
// ds_read_b128 from swizzled slots (2-way bank aliasing = free, m136).
// MEASURED PITFALLS (do not revisit): R5 128B-row banking; R7 nonzero imm
// offset on global_load_lds; R11 per-lane ROW scatter breaks coalescing;
// R13 unswizzled 64B rows -> 8-way conflicts.
// 128x128 tile, 4 waves (2x2 of 64x64).
//   Out[m][n] = bf16( a2[m] + c2[n] - 2 * sum_k A[m][k]*Cb[n][k] )
// ---------------------------------------------------------------------------
__global__ __launch_bounds__(256, 3) void gemm_d2_fused(const u8* __restrict__ Fq,
                                                        const u8* __restrict__ Cq,
                                                        const float* __restrict__ f2,
                                                        const float* __restrict__ c2,
                                                        bf16_t* __restrict__ Dfc,
                                                        bf16_t* __restrict__ Dcc) {
    __shared__ __align__(16) u8 As[2][128 * 64];   // [panel][row*64 + swizzled]
    __shared__ __align__(16) u8 Bs[2][128 * 64];

    const int tid  = threadIdx.x;
    const int wave = tid >> 6;
    const int lane = tid & 63;

    const int by = blockIdx.y;
    const u8* A; const float* a2v; bf16_t* Out; int bm;
    if (by < B_ROWS / 128) { A = Fq; a2v = f2; Out = Dfc; bm = by * 128; }
    else { A = Cq; a2v = c2; Out = Dcc; bm = (by - B_ROWS / 128) * 128; }
    const int bn = blockIdx.x * 128;
    const int N = C_ROWS, K = D_DIM;

    const int wm = (wave >> 1) * 64;
    const int wn = (wave & 1) * 64;

    f32x4 acc[4][4] = {};

    const int c0   = wave * 2;            // staging chunks 2w, 2w+1 (16 rows)
    const int rsub = lane >> 2;           // 0..15 row within chunk
    // staging source chunk for slot (lane&3): (lane&3) ^ ((row>>1)&3)
    const int kbyt = ((lane & 3) ^ ((lane >> 3) & 3)) * 16;
    const int mrow = lane & 15;
    const int swr  = (mrow >> 1) & 3;     // read-side swizzle for this lane's row
    const int kg   = lane >> 4;           // k-group 0..3
    const int pnl  = kg >> 1;             // panel this lane reads
    const int half = kg & 1;              // 32B half within the 64B row
    const int sl0  = ((half * 2    ) ^ swr) * 16;  // swizzled slot of 1st 16B
    const int sl1  = ((half * 2 + 1) ^ swr) * 16;  // swizzled slot of 2nd 16B

    for (int k0 = 0; k0 < K; k0 += 128) {
        #pragma unroll
        for (int pn = 0; pn < 2; ++pn) {       // K-panel: k0 + pn*64 + [0,64)
            #pragma unroll
            for (int t = 0; t < 2; ++t) {
                int chunk = c0 + t;
                int row = chunk * 16 + rsub;
                const u8* gA = A  + (size_t)(bm + row) * K + (k0 + pn * 64 + kbyt);
                const u8* gB = Cq + (size_t)(bn + row) * K + (k0 + pn * 64 + kbyt);
                __builtin_amdgcn_global_load_lds(
                    (const __attribute__((address_space(1))) void*)gA,
                    (__attribute__((address_space(3))) void*)&As[pn][chunk * 1024], 16, 0, 0);
                __builtin_amdgcn_global_load_lds(
                    (const __attribute__((address_space(1))) void*)gB,
                    (__attribute__((address_space(3))) void*)&Bs[pn][chunk * 1024], 16, 0, 0);
            }
        }
        __syncthreads();

        // One K=128 step: 8 fragments x 2 ds_read_b128, 16 scaled MFMAs.
        i32x8 af[4], bf_[4];
        #pragma unroll
        for (int i = 0; i < 4; ++i) {
            int offA = (wm + i * 16 + mrow) * 64;
            int offB = (wn + i * 16 + mrow) * 64;
            i32x4 alo = *(const i32x4*)&As[pnl][offA + sl0];
            i32x4 ahi = *(const i32x4*)&As[pnl][offA + sl1];
            i32x4 blo = *(const i32x4*)&Bs[pnl][offB + sl0];
            i32x4 bhi = *(const i32x4*)&Bs[pnl][offB + sl1];
            af[i][0] = alo.x; af[i][1] = alo.y; af[i][2] = alo.z; af[i][3] = alo.w;
            af[i][4] = ahi.x; af[i][5] = ahi.y; af[i][6] = ahi.z; af[i][7] = ahi.w;
            bf_[i][0] = blo.x; bf_[i][1] = blo.y; bf_[i][2] = blo.z; bf_[i][3] = blo.w;
            bf_[i][4] = bhi.x; bf_[i][5] = bhi.y; bf_[i][6] = bhi.z; bf_[i][7] = bhi.w;
        }
        #pragma unroll
        for (int i = 0; i < 4; ++i)
            #pragma unroll
            for (int j = 0; j < 4; ++j)
                acc[i][j] = __builtin_amdgcn_mfma_scale_f32_16x16x128_f8f6f4(
                    af[i], bf_[j], acc[i][j],
                    0, 0,                 // cbsz=0 (A fp8 e4m3), blgp=0 (B fp8)
                    0, 0x7F7F7F7F,        // scale A: E8M0 1.0 in every byte
                    0, 0x7F7F7F7F);       // scale B: 1.0
        __syncthreads();
    }

    // Epilogue: d2 = a2[m] + c2[n] - 2*dot, stored bf16.
    // C/D layout shape-determined, dtype-independent (m121-128):
    // col=lane&15, row=(lane>>4)*4+reg
    const int ncol = lane & 15;
    const int r4   = (lane >> 4) * 4;
    #pragma unroll
    for (int i = 0; i < 4; ++i) {
        #pragma unroll
        for (int r = 0; r < 4; ++r) {
            int m = bm + wm + i * 16 + r4 + r;
            float am = a2v[m];
            #pragma unroll
            for (int j = 0; j < 4; ++j) {
                int n = bn + wn + j * 16 + ncol;
                Out[(size_t)m * N + n] = (bf16_t)(am + c2[n] - 2.0f * acc[i][j][r]);
            }
        }
    }
}

// ---------------------------------------------------------------------------
// select v3: bf16 distance rows, vectorized 16B loads.
// Iterative argmin w/ exclusion over Dfc row; on-demand trust from Dcc:
//   label in near3[sel]  <=>  #{ j : (Dcc[sel][j], j) <lex (Dcc[sel][label],
//   label) } < NEAREST   (stable argsort -> lexicographic order)
// Ownership: lane l, group g, sub e: n = g*512 + l*8 + e; excl bit g*8+e.
// 4 waves/block, one row per wave; one atomicAdd per block onto out.
// ---------------------------------------------------------------------------
__global__ __launch_bounds__(256) void select_kernel(const bf16_t* __restrict__ Dfc,
                                                     const bf16_t* __restrict__ Dcc,
                                                     float* __restrict__ out, int C) {
    int wave = threadIdx.x >> 6, lane = threadIdx.x & 63;
    int b = blockIdx.x * 4 + wave;
    int label = b / NUM;
    const bf16_t* row = Dfc + (size_t)b * C;

    float vals[32];
    #pragma unroll
    for (int g = 0; g < 4; ++g) {
        bf16x8 v = *(const bf16x8*)(row + g * 512 + lane * 8);
        #pragma unroll
        for (int e = 0; e < 8; ++e) {
            int n = g * 512 + lane * 8 + e;
            float f = (float)v[e];
            vals[g * 8 + e] = (n == label) ? INFINITY : f;
        }
    }

    unsigned int excl = 0;
    float min_diff = 0.0f;
    int found = 0;
    for (int it = 0; it < MAX_ITER; ++it) {
        float bestv = INFINITY; int bestidx = 0x7fffffff;
        #pragma unroll
        for (int g = 0; g < 4; ++g)
            #pragma unroll
            for (int e = 0; e < 8; ++e) {
                int bit = g * 8 + e;
                if (excl & (1u << bit)) continue;
                float v = vals[bit];
                int idx = g * 512 + lane * 8 + e;
                if (v < bestv || (v == bestv && idx < bestidx)) { bestv = v; bestidx = idx; }
            }
        for (int off = 32; off >= 1; off >>= 1) {
            float ov = __shfl_down(bestv, off); int oi = __shfl_down(bestidx, off);
            if (ov < bestv || (ov == bestv && oi < bestidx)) { bestv = ov; bestidx = oi; }
        }
        int sel = __shfl(bestidx, 0);
        float selv = __shfl(bestv, 0);

        // --- on-demand trust: count lex-smaller entries of Dcc row sel ---
        const bf16_t* crow = Dcc + (size_t)sel * C;
        float dl = (float)crow[label];          // uniform address: broadcast
        int cnt = 0;
        #pragma unroll
        for (int g = 0; g < 4; ++g) {
            bf16x8 v = *(const bf16x8*)(crow + g * 512 + lane * 8);
            #pragma unroll
            for (int e = 0; e < 8; ++e) {
                int idx = g * 512 + lane * 8 + e;
                float f = (float)v[e];
                cnt += (f < dl || (f == dl && idx < label)) ? 1 : 0;
            }
        }
        #pragma unroll
        for (int off = 32; off >= 1; off >>= 1) cnt += __shfl_down(cnt, off);
        cnt = __shfl(cnt, 0);
        bool trusted = (cnt >= NEAREST);

        if (trusted) { min_diff = sqrtf(fmaxf(selv, 0.0f)); found = 1; break; }
        if (((sel >> 3) & 63) == lane) excl |= 1u << (((sel >> 9) << 3) | (sel & 7));
    }
    __shared__ float hs[4];
    if (lane == 0) {
        float same = sqrtf(fmaxf((float)row[label], 0.0f));
        float md = found ? min_diff : 0.0f;
        hs[wave] = fmaxf(MARGIN + same - md, 0.0f);
    }
    __syncthreads();
    if (threadIdx.x == 0)
        atomicAdd(out, (hs[0] + hs[1] + hs[2] + hs[3]) * (1.0f / (float)B_ROWS));
}

// ---------------------------------------------------------------------------
extern "C" void kernel_launch(void* const* d_in, const int* in_sizes, int n_in,
                              void* d_out, int out_size, void* d_ws, size_t ws_size,
                              hipStream_t stream) {
    const float* feature = (const float*)d_in[0];  // 4096 x 2048
    const float* centers = (const float*)d_in[1];  // 2048 x 2048
    float* out = (float*)d_out;                    // scalar

    // Workspace layout (distances bf16, quantized inputs fp8)
    bf16_t* Dfc  = (bf16_t*)d_ws;                            // 4096*2048 bf16
    bf16_t* Dcc  = Dfc + (size_t)B_ROWS * C_ROWS;            // 2048*2048 bf16
    u8*     Fq   = (u8*)(Dcc + (size_t)C_ROWS * C_ROWS);     // 4096*2048 fp8
    u8*     Cq   = Fq + (size_t)B_ROWS * D_DIM;              // 2048*2048 fp8
    float*  f2   = (float*)(Cq + (size_t)C_ROWS * D_DIM);    // 4096
    float*  c2   = f2 + B_ROWS;                              // 2048

    conv_rows<<<(B_ROWS + C_ROWS) / 4, 256, 0, stream>>>(feature, centers, Fq, Cq,
                                                         f2, c2, out);

    // Both distance matrices in one dispatch: grid (16, 32+16) = 768 blocks.
    gemm_d2_fused<<<dim3(C_ROWS / 128, B_ROWS / 128 + C_ROWS / 128), 256, 0, stream>>>(
        Fq, Cq, f2, c2, Dfc, Dcc);

    // select with on-demand trust (reads Dcc directly; no near3 dispatch).
    select_kernel<<<B_ROWS / 4, 256, 0, stream>>>(Dfc, Dcc, out, C_ROWS);
}